// Round 4
// baseline (38092.856 us; speedup 1.0000x reference)
//
#include <hip/hip_runtime.h>
#include <math.h>

constexpr int B_ = 128, S_ = 256, U_ = 512, H_ = 8, L_ = 4, MU_ = 2048, NC_ = 250;
constexpr int TOK_ = B_ * S_;     // 32768 tokens
constexpr int CHUNK_ = 8192;      // 32 batches per chunk (contiguous tokens)

__device__ __forceinline__ float gelu_f(float v) {
    // exact gelu: 0.5*x*(1+erf(x/sqrt(2)))  (jax.nn.gelu approximate=False)
    return 0.5f * v * (1.0f + erff(v * 0.70710678118654752440f));
}

// ---------------------------------------------------------------------------
// fp32 tiled GEMM: C = epilogue(A[MxK] @ W[KxN]).  BM=128 BN=64 BK=32,
// 256 threads, 8x4 acc/thread. M must be a multiple of 128 (all call sites).
// modes: 0 plain, 1 landmark-combine (w*(missing?empty:v)), 2 +pos_emb gather
// ---------------------------------------------------------------------------
struct GemmP {
    const float* A; int lda;
    const float* W; int ldb;
    float* C; int ldc;
    int M, N, K;
    const float* bias;
    int act;    // 0 none, 1 gelu
    int beta;   // 0 overwrite, 1 accumulate into C
    int mode;   // 0 plain, 1 combine, 2 posemb
    const float* miss; const float* empty; const float* wsc;
    const float* posemb; const int* posidx;
};

__global__ __launch_bounds__(256) void gemm_k(GemmP p) {
    __shared__ float As[32][132];   // [k][m] (128 + 4 pad)
    __shared__ float Bs[32][64];    // [k][n]
    const int bm = blockIdx.y * 128, bn = blockIdx.x * 64;
    const int tid = threadIdx.x;
    const int tx = tid & 15, ty = tid >> 4;   // tx: n-quad, ty: m-oct
    float acc[8][4] = {};
    const bool vecA = (p.lda & 3) == 0;
    const bool vecB = (p.ldb & 3) == 0;
    for (int k0 = 0; k0 < p.K; k0 += 32) {
        if (vecA) {
#pragma unroll
            for (int i = 0; i < 4; i++) {        // 1024 quads: A 128x32
                int e = tid + i * 256;
                int m = e >> 3, kg = (e & 7) * 4;
                int gk = k0 + kg;
                float4 v = {0.f, 0.f, 0.f, 0.f};
                if (gk + 3 < p.K) {
                    v = *reinterpret_cast<const float4*>(&p.A[(size_t)(bm + m) * p.lda + gk]);
                } else if (gk < p.K) {
                    const float* ap = &p.A[(size_t)(bm + m) * p.lda];
                    float t[4];
#pragma unroll
                    for (int j = 0; j < 4; j++) t[j] = (gk + j < p.K) ? ap[gk + j] : 0.0f;
                    v = {t[0], t[1], t[2], t[3]};
                }
                As[kg + 0][m] = v.x; As[kg + 1][m] = v.y;
                As[kg + 2][m] = v.z; As[kg + 3][m] = v.w;
            }
        } else {
#pragma unroll
            for (int i = 0; i < 16; i++) {
                int e = tid + i * 256;
                int m = e >> 5, kk = e & 31;
                int gk = k0 + kk;
                float v = 0.0f;
                if (gk < p.K) v = p.A[(size_t)(bm + m) * p.lda + gk];
                As[kk][m] = v;
            }
        }
        if (vecB) {
#pragma unroll
            for (int i = 0; i < 2; i++) {        // 512 quads: B 32x64
                int e = tid + i * 256;
                int kk = e >> 4, ng = (e & 15) * 4;
                int gk = k0 + kk, gn = bn + ng;
                float4 v = {0.f, 0.f, 0.f, 0.f};
                if (gk < p.K) {
                    if (gn + 3 < p.N) {
                        v = *reinterpret_cast<const float4*>(&p.W[(size_t)gk * p.ldb + gn]);
                    } else {
                        float t[4];
#pragma unroll
                        for (int j = 0; j < 4; j++)
                            t[j] = (gn + j < p.N) ? p.W[(size_t)gk * p.ldb + gn + j] : 0.0f;
                        v = {t[0], t[1], t[2], t[3]};
                    }
                }
                *reinterpret_cast<float4*>(&Bs[kk][ng]) = v;
            }
        } else {
#pragma unroll
            for (int i = 0; i < 8; i++) {
                int e = tid + i * 256;
                int kk = e >> 6, n = e & 63;
                int gk = k0 + kk, gn = bn + n;
                float v = 0.0f;
                if (gk < p.K && gn < p.N) v = p.W[(size_t)gk * p.ldb + gn];
                Bs[kk][n] = v;
            }
        }
        __syncthreads();
#pragma unroll
        for (int kk = 0; kk < 32; kk++) {
            float4 a0 = *reinterpret_cast<const float4*>(&As[kk][ty * 8]);
            float4 a1 = *reinterpret_cast<const float4*>(&As[kk][ty * 8 + 4]);
            float4 bf = *reinterpret_cast<const float4*>(&Bs[kk][tx * 4]);
            float a8[8] = {a0.x, a0.y, a0.z, a0.w, a1.x, a1.y, a1.z, a1.w};
            float b4[4] = {bf.x, bf.y, bf.z, bf.w};
#pragma unroll
            for (int i = 0; i < 8; i++)
#pragma unroll
                for (int j = 0; j < 4; j++)
                    acc[i][j] = fmaf(a8[i], b4[j], acc[i][j]);
        }
        __syncthreads();
    }
#pragma unroll
    for (int i = 0; i < 8; i++) {
        int m = bm + ty * 8 + i;
#pragma unroll
        for (int j = 0; j < 4; j++) {
            int n = bn + tx * 4 + j;
            if (n >= p.N) continue;
            float v = acc[i][j];
            if (p.bias) v += p.bias[n];
            if (p.act == 1) v = gelu_f(v);
            if (p.mode == 1) {
                if (p.miss[m] != 0.0f) v = p.empty[n];
                v *= *p.wsc;
            } else if (p.mode == 2) {
                v += p.posemb[(size_t)p.posidx[m] * U_ + n];
            }
            size_t ci = (size_t)m * p.ldc + n;
            if (p.beta) v += p.C[ci];
            p.C[ci] = v;
        }
    }
}

// ---------------------------------------------------------------------------
// Fused attention for one (b,h) of a 32-batch chunk. K,V staged in LDS,
// shuffle softmax. qkv row layout: q(0..511)|k(512..1023)|v(1024..1535);
// per-head slice h*64. z overwrites the q slot.
// ---------------------------------------------------------------------------
__global__ __launch_bounds__(256) void attn_k(float* xq, const float* maskv) {
    __shared__ float Ks[S_][65];
    __shared__ float Vs[S_][65];
    const int b = blockIdx.x >> 3, h = blockIdx.x & 7;
    const int tid = threadIdx.x;
    const size_t base = (size_t)b * S_ * 1536 + h * 64;
    for (int e = tid; e < S_ * 64; e += 256) {
        int r = e >> 6, c = e & 63;
        Ks[r][c] = xq[base + (size_t)r * 1536 + 512 + c];
        Vs[r][c] = xq[base + (size_t)r * 1536 + 1024 + c];
    }
    __syncthreads();
    const int wave = tid >> 6, lane = tid & 63;
    float biasv[4];
#pragma unroll
    for (int t = 0; t < 4; t++)
        biasv[t] = (maskv[b * S_ + t * 64 + lane] != 0.0f) ? 0.0f : -1e9f;
    for (int row = wave; row < S_; row += 4) {
        float q = xq[base + (size_t)row * 1536 + lane];
        float s[4] = {0.f, 0.f, 0.f, 0.f};
#pragma unroll 8
        for (int d = 0; d < 64; d++) {
            float qv = __shfl(q, d);
#pragma unroll
            for (int t = 0; t < 4; t++)
                s[t] = fmaf(qv, Ks[t * 64 + lane][d], s[t]);
        }
#pragma unroll
        for (int t = 0; t < 4; t++) s[t] = s[t] * 0.125f + biasv[t];
        float mx = fmaxf(fmaxf(s[0], s[1]), fmaxf(s[2], s[3]));
#pragma unroll
        for (int o = 32; o > 0; o >>= 1) mx = fmaxf(mx, __shfl_xor(mx, o));
        float pr[4], sum = 0.0f;
#pragma unroll
        for (int t = 0; t < 4; t++) { pr[t] = __expf(s[t] - mx); sum += pr[t]; }
#pragma unroll
        for (int o = 32; o > 0; o >>= 1) sum += __shfl_xor(sum, o);
        float inv = 1.0f / sum;
#pragma unroll
        for (int t = 0; t < 4; t++) pr[t] *= inv;
        float acc = 0.0f;
#pragma unroll
        for (int t = 0; t < 4; t++)
#pragma unroll 8
            for (int jl = 0; jl < 64; jl++) {
                float pt = __shfl(pr[t], jl);
                acc = fmaf(pt, Vs[t * 64 + jl][lane], acc);
            }
        xq[base + (size_t)row * 1536 + lane] = acc;   // z into q slot
    }
}

// ---------------------------------------------------------------------------
// Per-token preprocessing: normalize coords, write group feature rows,
// group sums -> missing flags.
// FIX (R2): 66 landmarks > 64 lanes — lanes 64,65 were never processed,
// leaving f_pose[.., 6..9] poisoned. Loop i = lane; i < 66; i += 64.
// ---------------------------------------------------------------------------
__global__ __launch_bounds__(64) void prep_tok_k(
        const float* frames,
        const float* lm, const float* ls, const float* hm, const float* hs,
        const float* pm, const float* ps,
        float* f_lips, float* f_hand, float* f_pose, float* missing) {
    const int tok = blockIdx.x;
    const int lane = threadIdx.x;
    float g0 = 0.0f, g1 = 0.0f, g2 = 0.0f;
    for (int i = lane; i < 66; i += 64) {
        float xx = frames[((size_t)tok * 66 + i) * 3 + 0];
        float yy = frames[((size_t)tok * 66 + i) * 3 + 1];
        const float* m; const float* s; int li;
        if (i < 40)      { m = lm; s = ls; li = i; }
        else if (i < 61) { m = hm; s = hs; li = i - 40; }
        else             { m = pm; s = ps; li = i - 61; }
        float vx = (xx == 0.0f) ? 0.0f : (xx - m[li * 2 + 0]) / s[li * 2 + 0];
        float vy = (yy == 0.0f) ? 0.0f : (yy - m[li * 2 + 1]) / s[li * 2 + 1];
        if (i < 40) {
            f_lips[(size_t)tok * 80 + li * 2 + 0] = vx;
            f_lips[(size_t)tok * 80 + li * 2 + 1] = vy;
            g0 += vx + vy;
        } else if (i < 61) {
            f_hand[(size_t)tok * 42 + li * 2 + 0] = vx;
            f_hand[(size_t)tok * 42 + li * 2 + 1] = vy;
            g1 += vx + vy;
        } else {
            f_pose[(size_t)tok * 10 + li * 2 + 0] = vx;
            f_pose[(size_t)tok * 10 + li * 2 + 1] = vy;
            g2 += vx + vy;
        }
    }
#pragma unroll
    for (int o = 32; o > 0; o >>= 1) {
        g0 += __shfl_xor(g0, o);
        g1 += __shfl_xor(g1, o);
        g2 += __shfl_xor(g2, o);
    }
    if (lane == 0) {
        missing[0 * TOK_ + tok] = (g0 == 0.0f) ? 1.0f : 0.0f;
        missing[1 * TOK_ + tok] = (g1 == 0.0f) ? 1.0f : 0.0f;
        missing[2 * TOK_ + tok] = (g2 == 0.0f) ? 1.0f : 0.0f;
    }
}

// Per-batch: mask, max-idx, pos_idx
__global__ __launch_bounds__(256) void prep_b_k(const float* nef, float* maskv, int* posidx) {
    const int b = blockIdx.x; const int s = threadIdx.x;
    __shared__ float red[256];
    float v = nef[b * S_ + s];
    red[s] = v;
    __syncthreads();
    for (int o = 128; o > 0; o >>= 1) {
        if (s < o) red[s] = fmaxf(red[s], red[s + o]);
        __syncthreads();
    }
    float mx = fmaxf(red[0], 1.0f);
    maskv[b * S_ + s] = (v != -1.0f) ? 1.0f : 0.0f;
    int ni = (int)((v / mx) * (float)S_);   // trunc toward zero, matches astype(int32)
    posidx[b * S_ + s] = (v == -1.0f) ? S_ : ni;
}

__global__ void lmw_k(const float* lm_w, float* w3) {
    if (threadIdx.x == 0) {
        float a = lm_w[0], b = lm_w[1], c = lm_w[2];
        float m = fmaxf(a, fmaxf(b, c));
        float ea = expf(a - m), eb = expf(b - m), ec = expf(c - m);
        float s = ea + eb + ec;
        w3[0] = ea / s; w3[1] = eb / s; w3[2] = ec / s;
    }
}

// Repack Wq/Wk/Wv (L,H,U,D) -> (L,U,1536) col j = sel*512 + h*64 + d; same biases
__global__ __launch_bounds__(256) void repack_k(
        const float* Wq, const float* Wk, const float* Wv,
        const float* bq, const float* bk, const float* bv,
        float* wqkv, float* bqkv) {
    size_t idx = (size_t)blockIdx.x * 256 + threadIdx.x;
    const size_t total = (size_t)L_ * U_ * 1536;
    if (idx < total) {
        int j = (int)(idx % 1536);
        size_t r = idx / 1536;
        int u = (int)(r % U_);
        int l = (int)(r / U_);
        int sel = j / 512, jj = j % 512;
        int h = jj / 64, d = jj % 64;
        const float* Ws = sel == 0 ? Wq : (sel == 1 ? Wk : Wv);
        wqkv[idx] = Ws[(((size_t)l * H_ + h) * U_ + u) * 64 + d];
    }
    if (idx < (size_t)L_ * 1536) {
        int j = (int)(idx % 1536); int l = (int)(idx / 1536);
        int sel = j / 512, jj = j % 512;
        int h = jj / 64, d = jj % 64;
        const float* bs = sel == 0 ? bq : (sel == 1 ? bk : bv);
        bqkv[idx] = bs[((size_t)l * H_ + h) * 64 + d];
    }
}

// Masked mean pool over S
__global__ __launch_bounds__(512) void pool_k(const float* x, const float* maskv, float* pooled) {
    const int b = blockIdx.x; const int u = threadIdx.x;
    __shared__ float red[256];
    if (u < 256) red[u] = maskv[b * S_ + u];
    __syncthreads();
    for (int o = 128; o > 0; o >>= 1) {
        if (u < o) red[u] += red[u + o];
        __syncthreads();
    }
    float msum = fmaxf(red[0], 1e-9f);
    float acc = 0.0f;
    for (int s = 0; s < S_; s++)
        acc += x[((size_t)b * S_ + s) * U_ + u] * maskv[b * S_ + s];
    pooled[b * U_ + u] = acc / msum;
}

extern "C" void kernel_launch(void* const* d_in, const int* in_sizes, int n_in,
                              void* d_out, int out_size, void* d_ws, size_t ws_size,
                              hipStream_t stream) {
    const float* frames     = (const float*)d_in[0];
    const float* nef        = (const float*)d_in[1];
    const float* lips_mean  = (const float*)d_in[2];
    const float* lips_std   = (const float*)d_in[3];
    const float* hand_mean  = (const float*)d_in[4];
    const float* hand_std   = (const float*)d_in[5];
    const float* pose_mean  = (const float*)d_in[6];
    const float* pose_std   = (const float*)d_in[7];
    const float* lips_empty = (const float*)d_in[8];
    const float* lips_W1    = (const float*)d_in[9];
    const float* lips_W2    = (const float*)d_in[10];
    const float* hand_empty = (const float*)d_in[11];
    const float* hand_W1    = (const float*)d_in[12];
    const float* hand_W2    = (const float*)d_in[13];
    const float* pose_empty = (const float*)d_in[14];
    const float* pose_W1    = (const float*)d_in[15];
    const float* pose_W2    = (const float*)d_in[16];
    const float* lm_w       = (const float*)d_in[17];
    const float* fc_W1      = (const float*)d_in[18];
    const float* fc_W2      = (const float*)d_in[19];
    const float* pos_emb    = (const float*)d_in[20];
    const float* Wq         = (const float*)d_in[21];
    const float* bq         = (const float*)d_in[22];
    const float* Wk         = (const float*)d_in[23];
    const float* bk         = (const float*)d_in[24];
    const float* Wv         = (const float*)d_in[25];
    const float* bv         = (const float*)d_in[26];
    const float* Wo         = (const float*)d_in[27];
    const float* bo         = (const float*)d_in[28];
    const float* Wm1        = (const float*)d_in[29];
    const float* bm1        = (const float*)d_in[30];
    const float* Wm2        = (const float*)d_in[31];
    const float* bm2        = (const float*)d_in[32];
    const float* clf_W      = (const float*)d_in[33];
    const float* clf_b      = (const float*)d_in[34];
    float* out = (float*)d_out;

    // ---- workspace layout (floats), all sub-arrays 16B-aligned; ~162 MB ----
    float* ws      = (float*)d_ws;
    float* x       = ws;                              // TOK*512
    float* wqkv    = x + (size_t)TOK_ * U_;           // L*512*1536
    float* bqkv    = wqkv + (size_t)L_ * U_ * 1536;   // L*1536
    float* missing = bqkv + L_ * 1536;                // 3*TOK
    float* maskv   = missing + 3 * TOK_;              // TOK
    int*   posidx  = (int*)(maskv + TOK_);            // TOK
    float* w3      = (float*)(posidx + TOK_);         // 4
    float* pooled  = w3 + 4;                          // B*512
    float* scratch = pooled + B_ * U_;                // TOK*644 floats (84.4 MB)
    // frontend views into scratch:
    float* f_lips  = scratch;                         // TOK*80
    float* f_hand  = f_lips + (size_t)TOK_ * 80;      // TOK*42
    float* f_pose  = f_hand + (size_t)TOK_ * 42;      // TOK*10
    float* h1      = f_pose + (size_t)TOK_ * 10;      // TOK*512
    // layer views into scratch (frontend buffers dead by then):
    float* xqc     = scratch;                         // CHUNK*1536 qkv chunk
    float* hb      = scratch;                         // CHUNK*2048 MLP chunk

    lmw_k<<<1, 64, 0, stream>>>(lm_w, w3);
    prep_tok_k<<<TOK_, 64, 0, stream>>>(frames, lips_mean, lips_std, hand_mean,
                                        hand_std, pose_mean, pose_std,
                                        f_lips, f_hand, f_pose, missing);
    prep_b_k<<<B_, 256, 0, stream>>>(nef, maskv, posidx);
    repack_k<<<(L_ * U_ * 1536 + 255) / 256, 256, 0, stream>>>(Wq, Wk, Wv, bq, bk, bv, wqkv, bqkv);

    auto gemm = [&](const float* A, int lda, const float* W, int ldb, float* C, int ldc,
                    int M, int N, int K, const float* bias, int act, int beta, int mode,
                    const float* miss, const float* empty, const float* wsc,
                    const float* pe, const int* pidx) {
        GemmP p{A, lda, W, ldb, C, ldc, M, N, K, bias, act, beta, mode, miss, empty, wsc, pe, pidx};
        dim3 g((N + 63) / 64, (M + 127) / 128);
        gemm_k<<<g, 256, 0, stream>>>(p);
    };

    // ---- frontend: landmark embeds + weighted combine ----
    gemm(f_lips, 80, lips_W1, 512, h1, 512, TOK_, 512, 80, nullptr, 1, 0, 0,
         nullptr, nullptr, nullptr, nullptr, nullptr);
    gemm(h1, 512, lips_W2, 512, x, 512, TOK_, 512, 512, nullptr, 0, 0, 1,
         missing, lips_empty, w3 + 0, nullptr, nullptr);
    gemm(f_hand, 42, hand_W1, 512, h1, 512, TOK_, 512, 42, nullptr, 1, 0, 0,
         nullptr, nullptr, nullptr, nullptr, nullptr);
    gemm(h1, 512, hand_W2, 512, x, 512, TOK_, 512, 512, nullptr, 0, 1, 1,
         missing + TOK_, hand_empty, w3 + 1, nullptr, nullptr);
    gemm(f_pose, 10, pose_W1, 512, h1, 512, TOK_, 512, 10, nullptr, 1, 0, 0,
         nullptr, nullptr, nullptr, nullptr, nullptr);
    gemm(h1, 512, pose_W2, 512, x, 512, TOK_, 512, 512, nullptr, 0, 1, 1,
         missing + 2 * TOK_, pose_empty, w3 + 2, nullptr, nullptr);
    // fc + positional embedding
    gemm(x, 512, fc_W1, 512, h1, 512, TOK_, 512, 512, nullptr, 1, 0, 0,
         nullptr, nullptr, nullptr, nullptr, nullptr);
    gemm(h1, 512, fc_W2, 512, x, 512, TOK_, 512, 512, nullptr, 0, 0, 2,
         nullptr, nullptr, nullptr, pos_emb, posidx);

    // ---- transformer layers (chunked: 8192 tokens = 32 contiguous batches) ----
    for (int l = 0; l < L_; l++) {
        for (int c0 = 0; c0 < TOK_; c0 += CHUNK_) {
            gemm(x + (size_t)c0 * U_, 512, wqkv + (size_t)l * U_ * 1536, 1536, xqc, 1536,
                 CHUNK_, 1536, 512, bqkv + l * 1536, 0, 0, 0,
                 nullptr, nullptr, nullptr, nullptr, nullptr);
            attn_k<<<(CHUNK_ / S_) * H_, 256, 0, stream>>>(xqc, maskv + c0);
            gemm(xqc, 1536, Wo + (size_t)l * U_ * U_, 512, x + (size_t)c0 * U_, 512,
                 CHUNK_, 512, 512, bo + (size_t)l * U_, 0, 1, 0,
                 nullptr, nullptr, nullptr, nullptr, nullptr);
        }
        for (int c0 = 0; c0 < TOK_; c0 += CHUNK_) {
            gemm(x + (size_t)c0 * U_, 512, Wm1 + (size_t)l * U_ * MU_, MU_, hb, MU_,
                 CHUNK_, MU_, 512, bm1 + (size_t)l * MU_, 1, 0, 0,
                 nullptr, nullptr, nullptr, nullptr, nullptr);
            gemm(hb, MU_, Wm2 + (size_t)l * MU_ * U_, 512, x + (size_t)c0 * U_, 512,
                 CHUNK_, 512, MU_, bm2 + (size_t)l * U_, 0, 1, 0,
                 nullptr, nullptr, nullptr, nullptr, nullptr);
        }
    }

    // ---- pool + classifier ----
    pool_k<<<B_, 512, 0, stream>>>(x, maskv, pooled);
    gemm(pooled, 512, clf_W, 250, out, 250, B_, NC_, 512, clf_b, 0, 0, 0,
         nullptr, nullptr, nullptr, nullptr, nullptr);
}

// Round 6
// 9995.845 us; speedup vs baseline: 3.8109x; 3.8109x over previous
//
#include <hip/hip_runtime.h>
#include <hip/hip_bf16.h>
#include <math.h>

typedef unsigned short u16;
constexpr int B_ = 128, S_ = 256, U_ = 512, H_ = 8, L_ = 4, MU_ = 2048, NC_ = 250;
constexpr int TOK_ = B_ * S_;     // 32768 tokens
constexpr int CHUNK_ = 8192;      // 32 batches per chunk

using bf16x8 = __attribute__((ext_vector_type(8))) short;   // 8 bf16 = 4 VGPR
using f32x4  = __attribute__((ext_vector_type(4))) float;

__device__ __forceinline__ float gelu_f(float v) {
    return 0.5f * v * (1.0f + erff(v * 0.70710678118654752440f));
}
__device__ __forceinline__ u16 f2b(float f) {
    __hip_bfloat16 h = __float2bfloat16(f);   // RNE
    return *reinterpret_cast<u16*>(&h);
}
__device__ __forceinline__ float b2f(u16 u) { union { unsigned i; float f; } c; c.i = (unsigned)u << 16; return c.f; }
__device__ __forceinline__ float blo(unsigned w) { union { unsigned i; float f; } c; c.i = w << 16; return c.f; }
__device__ __forceinline__ float bhi(unsigned w) { union { unsigned i; float f; } c; c.i = w & 0xffff0000u; return c.f; }

// ---------------------------------------------------------------------------
// bf16 MFMA GEMM: C = epilogue(A[MxK]bf16 @ Wt[NxK]bf16^T).
// BM=BN=128, BK=32, 256 threads = 4 waves (2x2), wave tile 64x64 (4x4 frags of
// 16x16x32). LDS [128][40] bf16 (pad 40 -> only 2-way bank aliasing, free).
// A frag: row=l&15, k=(l>>4)*8+j ; B frag (from Wt rows): col=l&15, same k.
// C/D: col=lane&15, row=(lane>>4)*4+reg  [m89-verified].
// K must be a multiple of 32 (buffers zero-padded); M a multiple of 128.
// ---------------------------------------------------------------------------
struct GemmP {
    const u16* A; int lda;
    const u16* Wt; int ldb;   // [N][ldb], ldb = Kpad
    float* C32; u16* C16; int ldc;
    int M, N, K;
    const float* bias;
    int act;    // 1 = gelu
    int beta;   // 1 = accumulate into C32
    int mode;   // 0 plain, 1 combine, 2 posemb
    const float* miss; const float* empty; const float* wsc;
    const float* posemb; const int* posidx;
};

__global__ __launch_bounds__(256) void gemm16_k(GemmP p) {
    __shared__ __align__(16) u16 As[128 * 40];
    __shared__ __align__(16) u16 Bs[128 * 40];
    const int bm = blockIdx.y * 128, bn = blockIdx.x * 128;
    const int tid = threadIdx.x;
    const int wave = tid >> 6, lane = tid & 63;
    const int wm = wave >> 1, wn = wave & 1;
    f32x4 acc[4][4];
#pragma unroll
    for (int i = 0; i < 4; i++)
#pragma unroll
        for (int j = 0; j < 4; j++) acc[i][j] = {0.f, 0.f, 0.f, 0.f};
    const bf16x8* aF[4]; const bf16x8* bF[4];
#pragma unroll
    for (int i = 0; i < 4; i++) {
        aF[i] = reinterpret_cast<const bf16x8*>(&As[(wm * 64 + i * 16 + (lane & 15)) * 40 + (lane >> 4) * 8]);
        bF[i] = reinterpret_cast<const bf16x8*>(&Bs[(wn * 64 + i * 16 + (lane & 15)) * 40 + (lane >> 4) * 8]);
    }
    for (int k0 = 0; k0 < p.K; k0 += 32) {
#pragma unroll
        for (int i = 0; i < 2; i++) {        // stage A,B tiles: 128 rows x 32 bf16
            int e = tid + i * 256;
            int row = e >> 2, seg = e & 3;   // 4 x 16B segments per row
            uint4 va = *reinterpret_cast<const uint4*>(&p.A[(size_t)(bm + row) * p.lda + k0 + seg * 8]);
            *reinterpret_cast<uint4*>(&As[row * 40 + seg * 8]) = va;
            int nrow = bn + row;
            uint4 vb = {0u, 0u, 0u, 0u};
            if (nrow < p.N) vb = *reinterpret_cast<const uint4*>(&p.Wt[(size_t)nrow * p.ldb + k0 + seg * 8]);
            *reinterpret_cast<uint4*>(&Bs[row * 40 + seg * 8]) = vb;
        }
        __syncthreads();
        bf16x8 aR[4], bR[4];
#pragma unroll
        for (int i = 0; i < 4; i++) { aR[i] = *aF[i]; bR[i] = *bF[i]; }
#pragma unroll
        for (int i = 0; i < 4; i++)
#pragma unroll
            for (int j = 0; j < 4; j++)
                acc[i][j] = __builtin_amdgcn_mfma_f32_16x16x32_bf16(aR[i], bR[j], acc[i][j], 0, 0, 0);
        __syncthreads();
    }
#pragma unroll
    for (int j = 0; j < 4; j++) {
        int n = bn + wn * 64 + j * 16 + (lane & 15);
        if (n >= p.N) continue;
        float bia = p.bias ? p.bias[n] : 0.0f;
#pragma unroll
        for (int i = 0; i < 4; i++) {
            int m0 = bm + wm * 64 + i * 16 + (lane >> 4) * 4;
#pragma unroll
            for (int r = 0; r < 4; r++) {
                int m = m0 + r;
                float v = acc[i][j][r] + bia;
                if (p.act) v = gelu_f(v);
                if (p.mode == 1) {
                    if (p.miss[m] != 0.0f) v = p.empty[n];
                    v *= *p.wsc;
                } else if (p.mode == 2) {
                    v += p.posemb[(size_t)p.posidx[m] * U_ + n];
                }
                size_t ci = (size_t)m * p.ldc + n;
                if (p.beta) v += p.C32[ci];
                if (p.C32) p.C32[ci] = v;
                if (p.C16) p.C16[ci] = f2b(v);
            }
        }
    }
}

// ---------------------------------------------------------------------------
// Fused attention per (b,h); bf16 in (QKV rows q|k|v of 1536), bf16 z out.
// K,V staged to LDS fp32; QK via shfl broadcast of q; PV via LDS P-row
// broadcast (uniform-address float4 reads, same-wave write->read is in-order).
// ---------------------------------------------------------------------------
__global__ __launch_bounds__(256) void attn_k(const u16* __restrict__ xq, u16* __restrict__ z,
                                              const float* __restrict__ maskv) {
    __shared__ float Ks[S_][65];
    __shared__ float Vs[S_][65];
    __shared__ float Ps[4][256];
    const int b = blockIdx.x >> 3, h = blockIdx.x & 7;
    const int tid = threadIdx.x;
    const size_t base = (size_t)b * S_ * 1536 + h * 64;
    for (int e = tid; e < S_ * 8; e += 256) {
        int r = e >> 3, c8 = (e & 7) * 8;
        const size_t ro = base + (size_t)r * 1536;
        uint4 kv = *reinterpret_cast<const uint4*>(&xq[ro + 512 + c8]);
        uint4 vv = *reinterpret_cast<const uint4*>(&xq[ro + 1024 + c8]);
        float* kd = &Ks[r][c8]; float* vd = &Vs[r][c8];
        kd[0] = blo(kv.x); kd[1] = bhi(kv.x); kd[2] = blo(kv.y); kd[3] = bhi(kv.y);
        kd[4] = blo(kv.z); kd[5] = bhi(kv.z); kd[6] = blo(kv.w); kd[7] = bhi(kv.w);
        vd[0] = blo(vv.x); vd[1] = bhi(vv.x); vd[2] = blo(vv.y); vd[3] = bhi(vv.y);
        vd[4] = blo(vv.z); vd[5] = bhi(vv.z); vd[6] = blo(vv.w); vd[7] = bhi(vv.w);
    }
    __syncthreads();
    const int wave = tid >> 6, lane = tid & 63;
    float biasv[4];
#pragma unroll
    for (int t = 0; t < 4; t++)
        biasv[t] = (maskv[b * S_ + t * 64 + lane] != 0.0f) ? 0.0f : -1e9f;
    for (int row = wave; row < S_; row += 4) {
        float q = b2f(xq[base + (size_t)row * 1536 + lane]);
        float s[4] = {0.f, 0.f, 0.f, 0.f};
#pragma unroll 8
        for (int d = 0; d < 64; d++) {
            float qv = __shfl(q, d);
#pragma unroll
            for (int t = 0; t < 4; t++)
                s[t] = fmaf(qv, Ks[t * 64 + lane][d], s[t]);
        }
#pragma unroll
        for (int t = 0; t < 4; t++) s[t] = s[t] * 0.125f + biasv[t];
        float mx = fmaxf(fmaxf(s[0], s[1]), fmaxf(s[2], s[3]));
#pragma unroll
        for (int o = 32; o > 0; o >>= 1) mx = fmaxf(mx, __shfl_xor(mx, o));
        float pr[4], sum = 0.0f;
#pragma unroll
        for (int t = 0; t < 4; t++) { pr[t] = __expf(s[t] - mx); sum += pr[t]; }
#pragma unroll
        for (int o = 32; o > 0; o >>= 1) sum += __shfl_xor(sum, o);
        float inv = 1.0f / sum;
#pragma unroll
        for (int t = 0; t < 4; t++) Ps[wave][t * 64 + lane] = pr[t] * inv;
        float acc = 0.0f;
        for (int j4 = 0; j4 < 256; j4 += 4) {
            float4 p4 = *reinterpret_cast<const float4*>(&Ps[wave][j4]);   // uniform addr: broadcast
            acc = fmaf(p4.x, Vs[j4 + 0][lane], acc);
            acc = fmaf(p4.y, Vs[j4 + 1][lane], acc);
            acc = fmaf(p4.z, Vs[j4 + 2][lane], acc);
            acc = fmaf(p4.w, Vs[j4 + 3][lane], acc);
        }
        z[((size_t)b * S_ + row) * U_ + h * 64 + lane] = f2b(acc);
    }
}

// ---------------------------------------------------------------------------
// Preprocess into ONE fused feature buffer f_feat[tok][192]:
// cols 0..95 lips (80 real + 16 zero-pad), 96..159 hand (42+22), 160..191
// pose (10+22). Also missing flags from normalized-value group sums.
// ---------------------------------------------------------------------------
__global__ __launch_bounds__(64) void prep_tok_k(
        const float* frames,
        const float* lm, const float* ls, const float* hm, const float* hs,
        const float* pm, const float* ps,
        u16* f_feat, float* missing) {
    const int tok = blockIdx.x;
    const int lane = threadIdx.x;
    float g0 = 0.f, g1 = 0.f, g2 = 0.f;
    for (int c = lane; c < 192; c += 64) {
        int grp, col;
        if (c < 96)       { grp = 0; col = c; }
        else if (c < 160) { grp = 1; col = c - 96; }
        else              { grp = 2; col = c - 160; }
        int li = col >> 1, coord = col & 1;
        int ng = grp == 0 ? 40 : (grp == 1 ? 21 : 5);
        float val = 0.0f;
        if (li < ng) {
            int gb = grp == 0 ? 0 : (grp == 1 ? 40 : 61);
            float t = frames[((size_t)tok * 66 + gb + li) * 3 + coord];
            const float* m = grp == 0 ? lm : (grp == 1 ? hm : pm);
            const float* s = grp == 0 ? ls : (grp == 1 ? hs : ps);
            val = (t == 0.0f) ? 0.0f : (t - m[li * 2 + coord]) / s[li * 2 + coord];
        }
        f_feat[(size_t)tok * 192 + c] = f2b(val);
        if (grp == 0) g0 += val; else if (grp == 1) g1 += val; else g2 += val;
    }
#pragma unroll
    for (int o = 32; o > 0; o >>= 1) {
        g0 += __shfl_xor(g0, o);
        g1 += __shfl_xor(g1, o);
        g2 += __shfl_xor(g2, o);
    }
    if (lane == 0) {
        missing[0 * TOK_ + tok] = (g0 == 0.0f) ? 1.0f : 0.0f;
        missing[1 * TOK_ + tok] = (g1 == 0.0f) ? 1.0f : 0.0f;
        missing[2 * TOK_ + tok] = (g2 == 0.0f) ? 1.0f : 0.0f;
    }
}

__global__ __launch_bounds__(256) void prep_b_k(const float* nef, float* maskv, int* posidx) {
    const int b = blockIdx.x; const int s = threadIdx.x;
    __shared__ float red[256];
    float v = nef[b * S_ + s];
    red[s] = v;
    __syncthreads();
    for (int o = 128; o > 0; o >>= 1) {
        if (s < o) red[s] = fmaxf(red[s], red[s + o]);
        __syncthreads();
    }
    float mx = fmaxf(red[0], 1.0f);
    maskv[b * S_ + s] = (v != -1.0f) ? 1.0f : 0.0f;
    int ni = (int)((v / mx) * (float)S_);   // trunc toward zero, matches astype(int32)
    posidx[b * S_ + s] = (v == -1.0f) ? S_ : ni;
}

__global__ void lmw_k(const float* lm_w, float* w3) {
    if (threadIdx.x == 0) {
        float a = lm_w[0], b = lm_w[1], c = lm_w[2];
        float m = fmaxf(a, fmaxf(b, c));
        float ea = expf(a - m), eb = expf(b - m), ec = expf(c - m);
        float s = ea + eb + ec;
        w3[0] = ea / s; w3[1] = eb / s; w3[2] = ec / s;
    }
}

// Generic transpose+convert: out[n][k] (bf16, stride Kpad, zero-pad k>=K) = in[k][n] (fp32, stride N)
__global__ __launch_bounds__(256) void tcvt_k(const float* in, int N, int K, u16* out, int Kpad) {
    __shared__ float T[32][33];
    const int k0 = blockIdx.x * 32, n0 = blockIdx.y * 32;
    const int tx = threadIdx.x & 31, ty = threadIdx.x >> 5;
    for (int a = ty; a < 32; a += 8) {
        float v = 0.0f;
        if (k0 + a < K && n0 + tx < N) v = in[(size_t)(k0 + a) * N + n0 + tx];
        T[a][tx] = v;
    }
    __syncthreads();
    for (int a = ty; a < 32; a += 8)
        if (n0 + a < N && k0 + tx < Kpad)
            out[(size_t)(n0 + a) * Kpad + k0 + tx] = f2b(T[tx][a]);
}

// QKV weights: Wt[l][sel*512+h*64+d][u] = Ws[l][h][u][d]  (bf16, stride 512)
__global__ __launch_bounds__(256) void qkvT_k(const float* Wq, const float* Wk, const float* Wv, u16* wt) {
    __shared__ float T[32][33];
    const int zid = blockIdx.z;                 // 0..95
    const int l = zid / 24, r = zid % 24, sel = r >> 3, h = r & 7;
    const float* Ws = sel == 0 ? Wq : (sel == 1 ? Wk : Wv);
    const float* in = Ws + (size_t)(l * 8 + h) * 512 * 64;         // [u][d]
    u16* out = wt + ((size_t)l * 1536 + sel * 512 + h * 64) * 512; // [d][u]
    const int u0 = blockIdx.x * 32, d0 = blockIdx.y * 32;
    const int tx = threadIdx.x & 31, ty = threadIdx.x >> 5;
    for (int a = ty; a < 32; a += 8)
        T[a][tx] = in[(size_t)(u0 + a) * 64 + d0 + tx];
    __syncthreads();
    for (int a = ty; a < 32; a += 8)
        out[(size_t)(d0 + a) * 512 + u0 + tx] = f2b(T[tx][a]);
}

__global__ void bqkv_k(const float* bq, const float* bk, const float* bv, float* bqkv) {
    int idx = blockIdx.x * 256 + threadIdx.x;
    if (idx < L_ * 1536) {
        int l = idx / 1536, j = idx % 1536;
        int sel = j >> 9, jj = j & 511, h = jj >> 6, d = jj & 63;
        const float* bs = sel == 0 ? bq : (sel == 1 ? bk : bv);
        bqkv[idx] = bs[(l * 8 + h) * 64 + d];
    }
}

__global__ __launch_bounds__(512) void pool_k(const float* x, const float* maskv, u16* pooled) {
    const int b = blockIdx.x; const int u = threadIdx.x;
    __shared__ float red[256];
    if (u < 256) red[u] = maskv[b * S_ + u];
    __syncthreads();
    for (int o = 128; o > 0; o >>= 1) {
        if (u < o) red[u] += red[u + o];
        __syncthreads();
    }
    float msum = fmaxf(red[0], 1e-9f);
    float acc = 0.0f;
    for (int s = 0; s < S_; s++)
        acc += x[((size_t)b * S_ + s) * U_ + u] * maskv[b * S_ + s];
    pooled[b * U_ + u] = f2b(acc / msum);
}

extern "C" void kernel_launch(void* const* d_in, const int* in_sizes, int n_in,
                              void* d_out, int out_size, void* d_ws, size_t ws_size,
                              hipStream_t stream) {
    const float* frames     = (const float*)d_in[0];
    const float* nef        = (const float*)d_in[1];
    const float* lips_mean  = (const float*)d_in[2];
    const float* lips_std   = (const float*)d_in[3];
    const float* hand_mean  = (const float*)d_in[4];
    const float* hand_std   = (const float*)d_in[5];
    const float* pose_mean  = (const float*)d_in[6];
    const float* pose_std   = (const float*)d_in[7];
    const float* lips_empty = (const float*)d_in[8];
    const float* lips_W1    = (const float*)d_in[9];
    const float* lips_W2    = (const float*)d_in[10];
    const float* hand_empty = (const float*)d_in[11];
    const float* hand_W1    = (const float*)d_in[12];
    const float* hand_W2    = (const float*)d_in[13];
    const float* pose_empty = (const float*)d_in[14];
    const float* pose_W1    = (const float*)d_in[15];
    const float* pose_W2    = (const float*)d_in[16];
    const float* lm_w       = (const float*)d_in[17];
    const float* fc_W1      = (const float*)d_in[18];
    const float* fc_W2      = (const float*)d_in[19];
    const float* pos_emb    = (const float*)d_in[20];
    const float* Wq         = (const float*)d_in[21];
    const float* bq         = (const float*)d_in[22];
    const float* Wk         = (const float*)d_in[23];
    const float* bk         = (const float*)d_in[24];
    const float* Wv         = (const float*)d_in[25];
    const float* bv         = (const float*)d_in[26];
    const float* Wo         = (const float*)d_in[27];
    const float* bo         = (const float*)d_in[28];
    const float* Wm1        = (const float*)d_in[29];
    const float* bm1        = (const float*)d_in[30];
    const float* Wm2        = (const float*)d_in[31];
    const float* bm2        = (const float*)d_in[32];
    const float* clf_W      = (const float*)d_in[33];
    const float* clf_b      = (const float*)d_in[34];
    float* out = (float*)d_out;

    // ---- workspace carve-out (~154 MB), 256B-aligned blocks ----
    char* wsb = (char*)d_ws;
    auto alloc = [&](size_t bytes) -> char* {
        char* p = wsb; wsb += (bytes + 255) & ~(size_t)255; return p;
    };
    float* x32    = (float*)alloc((size_t)TOK_ * 512 * 4);
    u16*   x16    = (u16*)  alloc((size_t)TOK_ * 512 * 2);
    u16*   wqkvT  = (u16*)  alloc((size_t)L_ * 1536 * 512 * 2);
    float* bqkv   = (float*)alloc(L_ * 1536 * 4);
    u16*   lw1T   = (u16*)  alloc(512 * 96 * 2);
    u16*   hw1T   = (u16*)  alloc(512 * 64 * 2);
    u16*   pw1T   = (u16*)  alloc(512 * 32 * 2);
    u16*   lw2T   = (u16*)  alloc(512 * 512 * 2);
    u16*   hw2T   = (u16*)  alloc(512 * 512 * 2);
    u16*   pw2T   = (u16*)  alloc(512 * 512 * 2);
    u16*   fc1T   = (u16*)  alloc(512 * 512 * 2);
    u16*   fc2T   = (u16*)  alloc(512 * 512 * 2);
    u16*   WoT    = (u16*)  alloc((size_t)L_ * 512 * 512 * 2);
    u16*   Wm1T   = (u16*)  alloc((size_t)L_ * 2048 * 512 * 2);
    u16*   Wm2T   = (u16*)  alloc((size_t)L_ * 512 * 2048 * 2);
    u16*   clfT   = (u16*)  alloc(256 * 512 * 2);
    float* missing= (float*)alloc(3 * TOK_ * 4);
    float* maskv  = (float*)alloc(TOK_ * 4);
    int*   posidx = (int*)  alloc(TOK_ * 4);
    float* w3     = (float*)alloc(16);
    u16*   pooled = (u16*)  alloc(128 * 512 * 2);
    u16*   R      = (u16*)  alloc((size_t)TOK_ * 512 * 2);   // shared scratch
    // f_feat (TOK*192) overlays x16: dead before the first x16 write
    // (pose-combine), alive only through the frontend W1 GEMMs.
    u16*   f_feat = x16;
    u16*   h1     = R;                          // TOK*512 (frontend)
    u16*   xq16   = R;                          // CHUNK*1536 (layers)
    u16*   z16    = R + (size_t)CHUNK_ * 1536;  // CHUNK*512
    u16*   hb16   = R;                          // CHUNK*2048

    // ---- one-time prep + weight convert/transpose ----
    lmw_k<<<1, 64, 0, stream>>>(lm_w, w3);
    prep_tok_k<<<TOK_, 64, 0, stream>>>(frames, lips_mean, lips_std, hand_mean,
                                        hand_std, pose_mean, pose_std,
                                        f_feat, missing);
    prep_b_k<<<B_, 256, 0, stream>>>(nef, maskv, posidx);
    qkvT_k<<<dim3(16, 2, 96), 256, 0, stream>>>(Wq, Wk, Wv, wqkvT);
    bqkv_k<<<(L_ * 1536 + 255) / 256, 256, 0, stream>>>(bq, bk, bv, bqkv);
    auto T = [&](const float* in, int N, int K, u16* o, int Kpad) {
        tcvt_k<<<dim3((Kpad + 31) / 32, (N + 31) / 32), 256, 0, stream>>>(in, N, K, o, Kpad);
    };
    T(lips_W1, 512, 80, lw1T, 96);
    T(hand_W1, 512, 42, hw1T, 64);
    T(pose_W1, 512, 10, pw1T, 32);
    T(lips_W2, 512, 512, lw2T, 512);
    T(hand_W2, 512, 512, hw2T, 512);
    T(pose_W2, 512, 512, pw2T, 512);
    T(fc_W1, 512, 512, fc1T, 512);
    T(fc_W2, 512, 512, fc2T, 512);
    for (int l = 0; l < L_; l++) {
        T(Wo + (size_t)l * 512 * 512, 512, 512, WoT + (size_t)l * 512 * 512, 512);
        T(Wm1 + (size_t)l * 512 * 2048, 2048, 512, Wm1T + (size_t)l * 2048 * 512, 512);
        T(Wm2 + (size_t)l * 2048 * 512, 512, 2048, Wm2T + (size_t)l * 512 * 2048, 2048);
    }
    T(clf_W, 250, 512, clfT, 512);

    auto G = [&](const u16* A, int lda, const u16* Wt, int ldb, float* C32, u16* C16, int ldc,
                 int M, int N, int K, const float* bias, int act, int beta, int mode,
                 const float* miss, const float* empty, const float* wsc,
                 const float* pe, const int* pidx) {
        GemmP p{A, lda, Wt, ldb, C32, C16, ldc, M, N, K, bias, act, beta, mode, miss, empty, wsc, pe, pidx};
        dim3 g((N + 127) / 128, M / 128);
        gemm16_k<<<g, 256, 0, stream>>>(p);
    };

    // ---- frontend (f_feat cols: 0 lips, 96 hand, 160 pose; lda 192) ----
    G(f_feat, 192, lw1T, 96, nullptr, h1, 512, TOK_, 512, 96, nullptr, 1, 0, 0,
      nullptr, nullptr, nullptr, nullptr, nullptr);
    G(h1, 512, lw2T, 512, x32, nullptr, 512, TOK_, 512, 512, nullptr, 0, 0, 1,
      missing, lips_empty, w3 + 0, nullptr, nullptr);
    G(f_feat + 96, 192, hw1T, 64, nullptr, h1, 512, TOK_, 512, 64, nullptr, 1, 0, 0,
      nullptr, nullptr, nullptr, nullptr, nullptr);
    G(h1, 512, hw2T, 512, x32, nullptr, 512, TOK_, 512, 512, nullptr, 0, 1, 1,
      missing + TOK_, hand_empty, w3 + 1, nullptr, nullptr);
    G(f_feat + 160, 192, pw1T, 32, nullptr, h1, 512, TOK_, 512, 32, nullptr, 1, 0, 0,
      nullptr, nullptr, nullptr, nullptr, nullptr);
    G(h1, 512, pw2T, 512, x32, x16, 512, TOK_, 512, 512, nullptr, 0, 1, 1,
      missing + 2 * TOK_, pose_empty, w3 + 2, nullptr, nullptr);
    G(x16, 512, fc1T, 512, nullptr, h1, 512, TOK_, 512, 512, nullptr, 1, 0, 0,
      nullptr, nullptr, nullptr, nullptr, nullptr);
    G(h1, 512, fc2T, 512, x32, x16, 512, TOK_, 512, 512, nullptr, 0, 0, 2,
      nullptr, nullptr, nullptr, pos_emb, posidx);

    // ---- transformer layers (chunks of 8192 tokens = 32 batches) ----
    for (int l = 0; l < L_; l++) {
        for (int c0 = 0; c0 < TOK_; c0 += CHUNK_) {
            G(x16 + (size_t)c0 * 512, 512, wqkvT + (size_t)l * 1536 * 512, 512,
              nullptr, xq16, 1536, CHUNK_, 1536, 512, bqkv + l * 1536, 0, 0, 0,
              nullptr, nullptr, nullptr, nullptr, nullptr);
            attn_k<<<(CHUNK_ / S_) * H_, 256, 0, stream>>>(xq16, z16, maskv + c0);
            G(z16, 512, WoT + (size_t)l * 512 * 512, 512,
              x32 + (size_t)c0 * 512, x16 + (size_t)c0 * 512, 512,
              CHUNK_, 512, 512, bo + (size_t)l * 512, 0, 1, 0,
              nullptr, nullptr, nullptr, nullptr, nullptr);
        }
        for (int c0 = 0; c0 < TOK_; c0 += CHUNK_) {
            G(x16 + (size_t)c0 * 512, 512, Wm1T + (size_t)l * 2048 * 512, 512,
              nullptr, hb16, 2048, CHUNK_, 2048, 512, bm1 + (size_t)l * 2048, 1, 0, 0,
              nullptr, nullptr, nullptr, nullptr, nullptr);
            G(hb16, 2048, Wm2T + (size_t)l * 512 * 2048, 2048,
              x32 + (size_t)c0 * 512, x16 + (size_t)c0 * 512, 512,
              CHUNK_, 512, 2048, bm2 + (size_t)l * 512, 0, 1, 0,
              nullptr, nullptr, nullptr, nullptr, nullptr);
        }
    }

    // ---- pool + classifier ----
    pool_k<<<B_, 512, 0, stream>>>(x32, maskv, pooled);
    G(pooled, 512, clfT, 512, out, nullptr, 250, 128, 250, 512, clf_b, 0, 0, 0,
      nullptr, nullptr, nullptr, nullptr, nullptr);
}

// Round 10
// 7311.589 us; speedup vs baseline: 5.2099x; 1.3671x over previous
//
#include <hip/hip_runtime.h>
#include <hip/hip_bf16.h>
#include <math.h>

typedef unsigned short u16;
constexpr int B_ = 128, S_ = 256, U_ = 512, H_ = 8, L_ = 4, MU_ = 2048, NC_ = 250;
constexpr int TOK_ = B_ * S_;     // 32768 tokens
constexpr int CHUNK_ = 8192;      // 32 batches per chunk
constexpr int SG_ = 8;            // batches per attention subgroup (Z = 64)

using bf16x8 = __attribute__((ext_vector_type(8))) short;   // 8 bf16 = 4 VGPR
using f32x4  = __attribute__((ext_vector_type(4))) float;

__device__ __forceinline__ float gelu_f(float v) {
    return 0.5f * v * (1.0f + erff(v * 0.70710678118654752440f));
}
__device__ __forceinline__ u16 f2b(float f) {
    __hip_bfloat16 h = __float2bfloat16(f);   // RNE
    return *reinterpret_cast<u16*>(&h);
}
__device__ __forceinline__ float b2f(u16 u) { union { unsigned i; float f; } c; c.i = (unsigned)u << 16; return c.f; }

// ---------------------------------------------------------------------------
// bf16 MFMA GEMM: C = epilogue(A[MxK]bf16 @ Wt[NxK]bf16^T), optionally batched
// over blockIdx.z with per-z base offsets (z = zb*2^zsh + hh).
// BM=BN=128, BK=32, 256 threads = 4 waves (2x2), wave tile 64x64.
// LDS [128][40] bf16 (pad 40 -> only 2-way bank aliasing, free).
// A frag: row=l&15, k=(l>>4)*8+j ; B frag (Wt rows): col=l&15, same k.
// C/D: col=lane&15, row=(lane>>4)*4+reg  [m89-verified].
// K multiple of 32; M multiple of 128 (all call sites).
// modes: 0 plain, 1 combine, 2 posemb, 3 attn-scale (v *= 0.125)
// ---------------------------------------------------------------------------
struct GemmP {
    const u16* A; int lda;
    const u16* Wt; int ldb;   // [N][ldb]
    float* C32; u16* C16; int ldc;
    int M, N, K;
    const float* bias;
    int act;    // 1 = gelu
    int beta;   // 1 = accumulate into C32
    int mode;
    const float* miss; const float* empty; const float* wsc;
    const float* posemb; const int* posidx;
    int zsh;    // log2(inner z group); 0 for unbatched
    long long aZb, aZh, wZb, wZh, cZb, cZh;
};

__global__ __launch_bounds__(256) void gemm16_k(GemmP p) {
    __shared__ __align__(16) u16 As[128 * 40];
    __shared__ __align__(16) u16 Bs[128 * 40];
    const int z = blockIdx.z;
    const int zb = z >> p.zsh, hh = z & ((1 << p.zsh) - 1);
    const u16* Ap = p.A + (size_t)((long long)zb * p.aZb + (long long)hh * p.aZh);
    const u16* Wp = p.Wt + (size_t)((long long)zb * p.wZb + (long long)hh * p.wZh);
    const size_t coff = (size_t)((long long)zb * p.cZb + (long long)hh * p.cZh);
    const int bm = blockIdx.y * 128, bn = blockIdx.x * 128;
    const int tid = threadIdx.x;
    const int wave = tid >> 6, lane = tid & 63;
    const int wm = wave >> 1, wn = wave & 1;
    f32x4 acc[4][4];
#pragma unroll
    for (int i = 0; i < 4; i++)
#pragma unroll
        for (int j = 0; j < 4; j++) acc[i][j] = {0.f, 0.f, 0.f, 0.f};
    const bf16x8* aF[4]; const bf16x8* bF[4];
#pragma unroll
    for (int i = 0; i < 4; i++) {
        aF[i] = reinterpret_cast<const bf16x8*>(&As[(wm * 64 + i * 16 + (lane & 15)) * 40 + (lane >> 4) * 8]);
        bF[i] = reinterpret_cast<const bf16x8*>(&Bs[(wn * 64 + i * 16 + (lane & 15)) * 40 + (lane >> 4) * 8]);
    }
    for (int k0 = 0; k0 < p.K; k0 += 32) {
#pragma unroll
        for (int i = 0; i < 2; i++) {        // stage A,B tiles: 128 rows x 32 bf16
            int e = tid + i * 256;
            int row = e >> 2, seg = e & 3;   // 4 x 16B segments per row
            uint4 va = *reinterpret_cast<const uint4*>(&Ap[(size_t)(bm + row) * p.lda + k0 + seg * 8]);
            *reinterpret_cast<uint4*>(&As[row * 40 + seg * 8]) = va;
            int nrow = bn + row;
            uint4 vb = {0u, 0u, 0u, 0u};
            if (nrow < p.N) vb = *reinterpret_cast<const uint4*>(&Wp[(size_t)nrow * p.ldb + k0 + seg * 8]);
            *reinterpret_cast<uint4*>(&Bs[row * 40 + seg * 8]) = vb;
        }
        __syncthreads();
        bf16x8 aR[4], bR[4];
#pragma unroll
        for (int i = 0; i < 4; i++) { aR[i] = *aF[i]; bR[i] = *bF[i]; }
#pragma unroll
        for (int i = 0; i < 4; i++)
#pragma unroll
            for (int j = 0; j < 4; j++)
                acc[i][j] = __builtin_amdgcn_mfma_f32_16x16x32_bf16(aR[i], bR[j], acc[i][j], 0, 0, 0);
        __syncthreads();
    }
#pragma unroll
    for (int j = 0; j < 4; j++) {
        int n = bn + wn * 64 + j * 16 + (lane & 15);
        if (n >= p.N) continue;
        float bia = p.bias ? p.bias[n] : 0.0f;
#pragma unroll
        for (int i = 0; i < 4; i++) {
            int m0 = bm + wm * 64 + i * 16 + (lane >> 4) * 4;
#pragma unroll
            for (int r = 0; r < 4; r++) {
                int m = m0 + r;
                float v = acc[i][j][r] + bia;
                if (p.act) v = gelu_f(v);
                if (p.mode == 1) {
                    if (p.miss[m] != 0.0f) v = p.empty[n];
                    v *= *p.wsc;
                } else if (p.mode == 2) {
                    v += p.posemb[(size_t)p.posidx[m] * U_ + n];
                } else if (p.mode == 3) {
                    v *= 0.125f;
                }
                size_t ci = coff + (size_t)m * p.ldc + n;
                if (p.beta) v += p.C32[ci];
                if (p.C32) p.C32[ci] = v;
                if (p.C16) p.C16[ci] = f2b(v);
            }
        }
    }
}

// ---------------------------------------------------------------------------
// Fused softmax + V-transpose for one attention subgroup (Z = 64 = 8b x 8h).
// Blocks [0,4096): softmax — one wave per S row (z = row>>8): mask -> -inf,
// max/sum via shfl, write bf16 P IN-PLACE over the f32 row (row stride 512
// u16; one wave owns a row; the shfl reductions force all lanes' loads to
// complete before any store issues -> safe).
// Blocks [4096,4160): transpose V[kv][d] -> vT[z][d][kv] via LDS tile.
// ---------------------------------------------------------------------------
__global__ __launch_bounds__(256) void sm_vt_k(float* __restrict__ S, const u16* __restrict__ xq,
                                               u16* __restrict__ vT, const float* __restrict__ maskm) {
    __shared__ u16 T[256 * 66];
    const int bid = blockIdx.x;
    const int tid = threadIdx.x;
    if (bid < 4096) {
        const int gw = (bid * 256 + tid) >> 6;       // global wave = row id
        const int lane = tid & 63;
        const int z = gw >> 8, m = gw & 255;
        const int bg = z >> 3;
        float4 s4 = *reinterpret_cast<const float4*>(&S[(size_t)z * 65536 + m * 256 + lane * 4]);
        float4 mk = *reinterpret_cast<const float4*>(&maskm[bg * 256 + lane * 4]);
        float s[4];
        s[0] = mk.x != 0.0f ? s4.x : -3.0e38f;
        s[1] = mk.y != 0.0f ? s4.y : -3.0e38f;
        s[2] = mk.z != 0.0f ? s4.z : -3.0e38f;
        s[3] = mk.w != 0.0f ? s4.w : -3.0e38f;
        float mx = fmaxf(fmaxf(s[0], s[1]), fmaxf(s[2], s[3]));
#pragma unroll
        for (int o = 32; o > 0; o >>= 1) mx = fmaxf(mx, __shfl_xor(mx, o));
        float pr[4], sum = 0.0f;
#pragma unroll
        for (int t = 0; t < 4; t++) { pr[t] = __expf(s[t] - mx); sum += pr[t]; }
#pragma unroll
        for (int o = 32; o > 0; o >>= 1) sum += __shfl_xor(sum, o);
        float inv = 1.0f / sum;
        ushort4 o4;
        o4.x = f2b(pr[0] * inv); o4.y = f2b(pr[1] * inv);
        o4.z = f2b(pr[2] * inv); o4.w = f2b(pr[3] * inv);
        *reinterpret_cast<ushort4*>(&reinterpret_cast<u16*>(S)[(size_t)z * 131072 + m * 512 + lane * 4]) = o4;
    } else {
        const int z = bid - 4096;                    // 0..63
        const u16* in = xq + (size_t)((z >> 3) * 256) * 1536 + 1024 + (z & 7) * 64;
        for (int e = tid; e < 16384; e += 256) {
            int kv = e >> 6, d = e & 63;
            T[kv * 66 + d] = in[(size_t)kv * 1536 + d];
        }
        __syncthreads();
        u16* o = vT + (size_t)z * 16384;
        for (int e = tid; e < 16384; e += 256) {
            int d = e >> 8, kv = e & 255;
            o[d * 256 + kv] = T[kv * 66 + d];
        }
    }
}

// ---------------------------------------------------------------------------
// Preprocess into ONE fused feature buffer f_feat[tok][192]:
// cols 0..95 lips (80 real + 16 zero-pad), 96..159 hand (42+22), 160..191
// pose (10+22). Also missing flags from normalized-value group sums.
// ---------------------------------------------------------------------------
__global__ __launch_bounds__(64) void prep_tok_k(
        const float* frames,
        const float* lm, const float* ls, const float* hm, const float* hs,
        const float* pm, const float* ps,
        u16* f_feat, float* missing) {
    const int tok = blockIdx.x;
    const int lane = threadIdx.x;
    float g0 = 0.f, g1 = 0.f, g2 = 0.f;
    for (int c = lane; c < 192; c += 64) {
        int grp, col;
        if (c < 96)       { grp = 0; col = c; }
        else if (c < 160) { grp = 1; col = c - 96; }
        else              { grp = 2; col = c - 160; }
        int li = col >> 1, coord = col & 1;
        int ng = grp == 0 ? 40 : (grp == 1 ? 21 : 5);
        float val = 0.0f;
        if (li < ng) {
            int gb = grp == 0 ? 0 : (grp == 1 ? 40 : 61);
            float t = frames[((size_t)tok * 66 + gb + li) * 3 + coord];
            const float* m = grp == 0 ? lm : (grp == 1 ? hm : pm);
            const float* s = grp == 0 ? ls : (grp == 1 ? hs : ps);
            val = (t == 0.0f) ? 0.0f : (t - m[li * 2 + coord]) / s[li * 2 + coord];
        }
        f_feat[(size_t)tok * 192 + c] = f2b(val);
        if (grp == 0) g0 += val; else if (grp == 1) g1 += val; else g2 += val;
    }
#pragma unroll
    for (int o = 32; o > 0; o >>= 1) {
        g0 += __shfl_xor(g0, o);
        g1 += __shfl_xor(g1, o);
        g2 += __shfl_xor(g2, o);
    }
    if (lane == 0) {
        missing[0 * TOK_ + tok] = (g0 == 0.0f) ? 1.0f : 0.0f;
        missing[1 * TOK_ + tok] = (g1 == 0.0f) ? 1.0f : 0.0f;
        missing[2 * TOK_ + tok] = (g2 == 0.0f) ? 1.0f : 0.0f;
    }
}

__global__ __launch_bounds__(256) void prep_b_k(const float* nef, float* maskv, int* posidx) {
    const int b = blockIdx.x; const int s = threadIdx.x;
    __shared__ float red[256];
    float v = nef[b * S_ + s];
    red[s] = v;
    __syncthreads();
    for (int o = 128; o > 0; o >>= 1) {
        if (s < o) red[s] = fmaxf(red[s], red[s + o]);
        __syncthreads();
    }
    float mx = fmaxf(red[0], 1.0f);
    maskv[b * S_ + s] = (v != -1.0f) ? 1.0f : 0.0f;
    int ni = (int)((v / mx) * (float)S_);   // trunc toward zero, matches astype(int32)
    posidx[b * S_ + s] = (v == -1.0f) ? S_ : ni;
}

__global__ void lmw_k(const float* lm_w, float* w3) {
    if (threadIdx.x == 0) {
        float a = lm_w[0], b = lm_w[1], c = lm_w[2];
        float m = fmaxf(a, fmaxf(b, c));
        float ea = expf(a - m), eb = expf(b - m), ec = expf(c - m);
        float s = ea + eb + ec;
        w3[0] = ea / s; w3[1] = eb / s; w3[2] = ec / s;
    }
}

// Generic transpose+convert: out[n][k] (bf16, stride Kpad, zero-pad k>=K) = in[k][n] (fp32, stride N)
__global__ __launch_bounds__(256) void tcvt_k(const float* in, int N, int K, u16* out, int Kpad) {
    __shared__ float T[32][33];
    const int k0 = blockIdx.x * 32, n0 = blockIdx.y * 32;
    const int tx = threadIdx.x & 31, ty = threadIdx.x >> 5;
    for (int a = ty; a < 32; a += 8) {
        float v = 0.0f;
        if (k0 + a < K && n0 + tx < N) v = in[(size_t)(k0 + a) * N + n0 + tx];
        T[a][tx] = v;
    }
    __syncthreads();
    for (int a = ty; a < 32; a += 8)
        if (n0 + a < N && k0 + tx < Kpad)
            out[(size_t)(n0 + a) * Kpad + k0 + tx] = f2b(T[tx][a]);
}

// QKV weights: Wt[l][sel*512+h*64+d][u] = Ws[l][h][u][d]  (bf16, stride 512)
__global__ __launch_bounds__(256) void qkvT_k(const float* Wq, const float* Wk, const float* Wv, u16* wt) {
    __shared__ float T[32][33];
    const int zid = blockIdx.z;                 // 0..95
    const int l = zid / 24, r = zid % 24, sel = r >> 3, h = r & 7;
    const float* Ws = sel == 0 ? Wq : (sel == 1 ? Wk : Wv);
    const float* in = Ws + (size_t)(l * 8 + h) * 512 * 64;         // [u][d]
    u16* out = wt + ((size_t)l * 1536 + sel * 512 + h * 64) * 512; // [d][u]
    const int u0 = blockIdx.x * 32, d0 = blockIdx.y * 32;
    const int tx = threadIdx.x & 31, ty = threadIdx.x >> 5;
    for (int a = ty; a < 32; a += 8)
        T[a][tx] = in[(size_t)(u0 + a) * 64 + d0 + tx];
    __syncthreads();
    for (int a = ty; a < 32; a += 8)
        out[(size_t)(d0 + a) * 512 + u0 + tx] = f2b(T[tx][a]);
}

__global__ void bqkv_k(const float* bq, const float* bk, const float* bv, float* bqkv) {
    int idx = blockIdx.x * 256 + threadIdx.x;
    if (idx < L_ * 1536) {
        int l = idx / 1536, j = idx % 1536;
        int sel = j >> 9, jj = j & 511, h = jj >> 6, d = jj & 63;
        const float* bs = sel == 0 ? bq : (sel == 1 ? bk : bv);
        bqkv[idx] = bs[(l * 8 + h) * 64 + d];
    }
}

__global__ __launch_bounds__(512) void pool_k(const float* x, const float* maskv, u16* pooled) {
    const int b = blockIdx.x; const int u = threadIdx.x;
    __shared__ float red[256];
    if (u < 256) red[u] = maskv[b * S_ + u];
    __syncthreads();
    for (int o = 128; o > 0; o >>= 1) {
        if (u < o) red[u] += red[u + o];
        __syncthreads();
    }
    float msum = fmaxf(red[0], 1e-9f);
    float acc = 0.0f;
    for (int s = 0; s < S_; s++)
        acc += x[((size_t)b * S_ + s) * U_ + u] * maskv[b * S_ + s];
    pooled[b * U_ + u] = f2b(acc / msum);
}

extern "C" void kernel_launch(void* const* d_in, const int* in_sizes, int n_in,
                              void* d_out, int out_size, void* d_ws, size_t ws_size,
                              hipStream_t stream) {
    const float* frames     = (const float*)d_in[0];
    const float* nef        = (const float*)d_in[1];
    const float* lips_mean  = (const float*)d_in[2];
    const float* lips_std   = (const float*)d_in[3];
    const float* hand_mean  = (const float*)d_in[4];
    const float* hand_std   = (const float*)d_in[5];
    const float* pose_mean  = (const float*)d_in[6];
    const float* pose_std   = (const float*)d_in[7];
    const float* lips_empty = (const float*)d_in[8];
    const float* lips_W1    = (const float*)d_in[9];
    const float* lips_W2    = (const float*)d_in[10];
    const float* hand_empty = (const float*)d_in[11];
    const float* hand_W1    = (const float*)d_in[12];
    const float* hand_W2    = (const float*)d_in[13];
    const float* pose_empty = (const float*)d_in[14];
    const float* pose_W1    = (const float*)d_in[15];
    const float* pose_W2    = (const float*)d_in[16];
    const float* lm_w       = (const float*)d_in[17];
    const float* fc_W1      = (const float*)d_in[18];
    const float* fc_W2      = (const float*)d_in[19];
    const float* pos_emb    = (const float*)d_in[20];
    const float* Wq         = (const float*)d_in[21];
    const float* bq         = (const float*)d_in[22];
    const float* Wk         = (const float*)d_in[23];
    const float* bk         = (const float*)d_in[24];
    const float* Wv         = (const float*)d_in[25];
    const float* bv         = (const float*)d_in[26];
    const float* Wo         = (const float*)d_in[27];
    const float* bo         = (const float*)d_in[28];
    const float* Wm1        = (const float*)d_in[29];
    const float* bm1        = (const float*)d_in[30];
    const float* Wm2        = (const float*)d_in[31];
    const float* bm2        = (const float*)d_in[32];
    const float* clf_W      = (const float*)d_in[33];
    const float* clf_b      = (const float*)d_in[34];
    float* out = (float*)d_out;

    // ---- workspace carve-out (~152 MB), 256B-aligned blocks ----
    char* wsb = (char*)d_ws;
    auto alloc = [&](size_t bytes) -> char* {
        char* p = wsb; wsb += (bytes + 255) & ~(size_t)255; return p;
    };
    float* x32    = (float*)alloc((size_t)TOK_ * 512 * 4);
    u16*   x16    = (u16*)  alloc((size_t)TOK_ * 512 * 2);
    u16*   wqkvT  = (u16*)  alloc((size_t)L_ * 1536 * 512 * 2);
    float* bqkv   = (float*)alloc(L_ * 1536 * 4);
    u16*   lw1T   = (u16*)  alloc(512 * 96 * 2);
    u16*   hw1T   = (u16*)  alloc(512 * 64 * 2);
    u16*   pw1T   = (u16*)  alloc(512 * 32 * 2);
    u16*   lw2T   = (u16*)  alloc(512 * 512 * 2);
    u16*   hw2T   = (u16*)  alloc(512 * 512 * 2);
    u16*   pw2T   = (u16*)  alloc(512 * 512 * 2);
    u16*   fc1T   = (u16*)  alloc(512 * 512 * 2);
    u16*   fc2T   = (u16*)  alloc(512 * 512 * 2);
    u16*   WoT    = (u16*)  alloc((size_t)L_ * 512 * 512 * 2);
    u16*   Wm1T   = (u16*)  alloc((size_t)L_ * 2048 * 512 * 2);
    u16*   Wm2T   = (u16*)  alloc((size_t)L_ * 512 * 2048 * 2);
    u16*   clfT   = (u16*)  alloc(256 * 512 * 2);
    float* missing= (float*)alloc(3 * TOK_ * 4);
    float* maskv  = (float*)alloc(TOK_ * 4);
    int*   posidx = (int*)  alloc(TOK_ * 4);
    float* w3     = (float*)alloc(16);
    u16*   pooled = (u16*)  alloc(128 * 512 * 2);
    u16*   R      = (u16*)  alloc((size_t)TOK_ * 512 * 2);   // shared scratch
    float* Sbuf   = (float*)alloc((size_t)SG_ * H_ * 256 * 256 * 4);  // 16.8 MB
    u16*   vTb    = (u16*)  alloc((size_t)SG_ * H_ * 64 * 256 * 2);   // 2.1 MB
    // f_feat (TOK*192) overlays x16: dead before the first x16 write.
    u16*   f_feat = x16;
    u16*   h1     = R;                          // TOK*512 (frontend)
    u16*   xq16   = R;                          // CHUNK*1536 (layers)
    u16*   z16    = R + (size_t)CHUNK_ * 1536;  // CHUNK*512
    u16*   hb16   = R;                          // CHUNK*2048

    // ---- one-time prep + weight convert/transpose ----
    lmw_k<<<1, 64, 0, stream>>>(lm_w, w3);
    prep_tok_k<<<TOK_, 64, 0, stream>>>(frames, lips_mean, lips_std, hand_mean,
                                        hand_std, pose_mean, pose_std,
                                        f_feat, missing);
    prep_b_k<<<B_, 256, 0, stream>>>(nef, maskv, posidx);
    qkvT_k<<<dim3(16, 2, 96), 256, 0, stream>>>(Wq, Wk, Wv, wqkvT);
    bqkv_k<<<(L_ * 1536 + 255) / 256, 256, 0, stream>>>(bq, bk, bv, bqkv);
    auto T = [&](const float* in, int N, int K, u16* o, int Kpad) {
        tcvt_k<<<dim3((Kpad + 31) / 32, (N + 31) / 32), 256, 0, stream>>>(in, N, K, o, Kpad);
    };
    T(lips_W1, 512, 80, lw1T, 96);
    T(hand_W1, 512, 42, hw1T, 64);
    T(pose_W1, 512, 10, pw1T, 32);
    T(lips_W2, 512, 512, lw2T, 512);
    T(hand_W2, 512, 512, hw2T, 512);
    T(pose_W2, 512, 512, pw2T, 512);
    T(fc_W1, 512, 512, fc1T, 512);
    T(fc_W2, 512, 512, fc2T, 512);
    for (int l = 0; l < L_; l++) {
        T(Wo + (size_t)l * 512 * 512, 512, 512, WoT + (size_t)l * 512 * 512, 512);
        T(Wm1 + (size_t)l * 512 * 2048, 2048, 512, Wm1T + (size_t)l * 2048 * 512, 512);
        T(Wm2 + (size_t)l * 2048 * 512, 512, 2048, Wm2T + (size_t)l * 512 * 2048, 2048);
    }
    T(clf_W, 250, 512, clfT, 512);

    auto G = [&](const u16* A, int lda, const u16* Wt, int ldb, float* C32, u16* C16, int ldc,
                 int M, int N, int K, const float* bias, int act, int beta, int mode,
                 const float* miss, const float* empty, const float* wsc,
                 const float* pe, const int* pidx) {
        GemmP p{};
        p.A = A; p.lda = lda; p.Wt = Wt; p.ldb = ldb;
        p.C32 = C32; p.C16 = C16; p.ldc = ldc;
        p.M = M; p.N = N; p.K = K;
        p.bias = bias; p.act = act; p.beta = beta; p.mode = mode;
        p.miss = miss; p.empty = empty; p.wsc = wsc; p.posemb = pe; p.posidx = pidx;
        p.zsh = 0;
        dim3 g((N + 127) / 128, M / 128, 1);
        gemm16_k<<<g, 256, 0, stream>>>(p);
    };

    // ---- frontend (f_feat cols: 0 lips, 96 hand, 160 pose; lda 192) ----
    G(f_feat, 192, lw1T, 96, nullptr, h1, 512, TOK_, 512, 96, nullptr, 1, 0, 0,
      nullptr, nullptr, nullptr, nullptr, nullptr);
    G(h1, 512, lw2T, 512, x32, nullptr, 512, TOK_, 512, 512, nullptr, 0, 0, 1,
      missing, lips_empty, w3 + 0, nullptr, nullptr);
    G(f_feat + 96, 192, hw1T, 64, nullptr, h1, 512, TOK_, 512, 64, nullptr, 1, 0, 0,
      nullptr, nullptr, nullptr, nullptr, nullptr);
    G(h1, 512, hw2T, 512, x32, nullptr, 512, TOK_, 512, 512, nullptr, 0, 1, 1,
      missing + TOK_, hand_empty, w3 + 1, nullptr, nullptr);
    G(f_feat + 160, 192, pw1T, 32, nullptr, h1, 512, TOK_, 512, 32, nullptr, 1, 0, 0,
      nullptr, nullptr, nullptr, nullptr, nullptr);
    G(h1, 512, pw2T, 512, x32, x16, 512, TOK_, 512, 512, nullptr, 0, 1, 1,
      missing + 2 * TOK_, pose_empty, w3 + 2, nullptr, nullptr);
    G(x16, 512, fc1T, 512, nullptr, h1, 512, TOK_, 512, 512, nullptr, 1, 0, 0,
      nullptr, nullptr, nullptr, nullptr, nullptr);
    G(h1, 512, fc2T, 512, x32, x16, 512, TOK_, 512, 512, nullptr, 0, 0, 2,
      nullptr, nullptr, nullptr, pos_emb, posidx);

    // ---- transformer layers ----
    for (int l = 0; l < L_; l++) {
        for (int c0 = 0; c0 < TOK_; c0 += CHUNK_) {
            // QKV projection for the chunk
            G(x16 + (size_t)c0 * 512, 512, wqkvT + (size_t)l * 1536 * 512, 512,
              nullptr, xq16, 1536, CHUNK_, 1536, 512, bqkv + l * 1536, 0, 0, 0,
              nullptr, nullptr, nullptr, nullptr, nullptr);
            // attention: subgroups of 8 batches (Z = 64 bh)
            for (int b0 = 0; b0 < CHUNK_ / S_; b0 += SG_) {
                u16* xqs = xq16 + (size_t)b0 * 256 * 1536;
                GemmP p1{};
                p1.A = xqs; p1.lda = 1536;
                p1.Wt = xqs + 512; p1.ldb = 1536;
                p1.C32 = Sbuf; p1.C16 = nullptr; p1.ldc = 256;
                p1.M = 256; p1.N = 256; p1.K = 64;
                p1.mode = 3; p1.zsh = 3;
                p1.aZb = 256LL * 1536; p1.aZh = 64;
                p1.wZb = 256LL * 1536; p1.wZh = 64;
                p1.cZb = 8LL * 65536; p1.cZh = 65536;
                gemm16_k<<<dim3(2, 2, SG_ * H_), 256, 0, stream>>>(p1);
                sm_vt_k<<<4096 + SG_ * H_, 256, 0, stream>>>(Sbuf, xqs, vTb, maskv + c0 + b0 * 256);
                GemmP p2{};
                p2.A = (const u16*)Sbuf; p2.lda = 512;
                p2.Wt = vTb; p2.ldb = 256;
                p2.C32 = nullptr; p2.C16 = z16 + (size_t)b0 * 256 * 512; p2.ldc = 512;
                p2.M = 256; p2.N = 64; p2.K = 256;
                p2.mode = 0; p2.zsh = 3;
                p2.aZb = 8LL * 131072; p2.aZh = 131072;
                p2.wZb = 8LL * 16384; p2.wZh = 16384;
                p2.cZb = 256LL * 512; p2.cZh = 64;
                gemm16_k<<<dim3(1, 2, SG_ * H_), 256, 0, stream>>>(p2);
            }
            // output projection + residual
            G(z16, 512, WoT + (size_t)l * 512 * 512, 512,
              x32 + (size_t)c0 * 512, x16 + (size_t)c0 * 512, 512,
              CHUNK_, 512, 512, bo + (size_t)l * 512, 0, 1, 0,
              nullptr, nullptr, nullptr, nullptr, nullptr);
        }
        for (int c0 = 0; c0 < TOK_; c0 += CHUNK_) {
            G(x16 + (size_t)c0 * 512, 512, Wm1T + (size_t)l * 2048 * 512, 512,
              nullptr, hb16, 2048, CHUNK_, 2048, 512, bm1 + (size_t)l * 2048, 1, 0, 0,
              nullptr, nullptr, nullptr, nullptr, nullptr);
            G(hb16, 2048, Wm2T + (size_t)l * 512 * 2048, 2048,
              x32 + (size_t)c0 * 512, x16 + (size_t)c0 * 512, 512,
              CHUNK_, 512, 2048, bm2 + (size_t)l * 512, 0, 1, 0,
              nullptr, nullptr, nullptr, nullptr, nullptr);
        }
    }

    // ---- pool + classifier ----
    pool_k<<<B_, 512, 0, stream>>>(x32, maskv, pooled);
    G(pooled, 512, clfT, 512, out, nullptr, 250, 128, 250, 512, clf_b, 0, 0, 0,
      nullptr, nullptr, nullptr, nullptr, nullptr);
}